// Round 12
// baseline (214.969 us; speedup 1.0000x reference)
//
#include <hip/hip_runtime.h>

#define KSZ   121
#define KMEAN 60
#define IMW   512
#define IMH   512
#define NPLANES 24   // 8 * 3

typedef float    f32x4 __attribute__((ext_vector_type(4)));
typedef float    f32x2 __attribute__((ext_vector_type(2)));
typedef int      i32x4 __attribute__((ext_vector_type(4)));
typedef __fp16   f16x2 __attribute__((ext_vector_type(2)));

// CK-style raw buffer intrinsics: HW bounds check returns 0 for OOB lanes.
__device__ f32x4 buf_load_x4(i32x4 srsrc, int voffset, int soffset, int aux)
    __asm("llvm.amdgcn.raw.buffer.load.v4f32");
__device__ float buf_load_f32(i32x4 srsrc, int voffset, int soffset, int aux)
    __asm("llvm.amdgcn.raw.buffer.load.f32");
__device__ void buf_store_f32(float data, i32x4 srsrc, int voffset, int soffset, int aux)
    __asm("llvm.amdgcn.raw.buffer.store.f32");

// SRD inputs MUST be wave-uniform (plane index is block-uniform here).
__device__ __forceinline__ i32x4 make_srd(const void* p, int bytes) {
    union { const void* p; unsigned u[2]; } a; a.p = p;
    i32x4 r;
    r.x = (int)__builtin_amdgcn_readfirstlane((int)a.u[0]);
    r.y = (int)__builtin_amdgcn_readfirstlane((int)a.u[1]);
    r.z = bytes;          // num_records: OOB load -> 0, OOB store -> dropped
    r.w = 0x00020000;     // raw dword SRD word3 (gfx9/gfx950)
    return r;
}

union HU { unsigned u; f16x2 h; };

__device__ __forceinline__ f32x2 h2unpk(unsigned u) {
    HU a; a.u = u;
    f32x2 r; r.x = (float)a.h.x; r.y = (float)a.h.y;
    return r;
}

// ---------------------------------------------------------------------------
// Kernel 1: taps w[0..120] (pad to 124 with 0) + edge-correction tables.
//   out[o] = sum_k w[k]*zpad[o+k-60] + edge0*L[o] + edgeN*R[o]
//   L[o] = P[59-o] (o<=59), R[o] = 1-P[571-o] (o>=452), P = prefix of w.
// ws: [0,128) taps, [128,640) L, [640,1152) R. (proven r5-r11)
// ---------------------------------------------------------------------------
__global__ __launch_bounds__(128) void weights_kernel(const float* __restrict__ sigma,
                                                      float* __restrict__ ws) {
    __shared__ float w[121];
    __shared__ float P[121];
    int t = threadIdx.x;
    float s = sigma[0] * 8.0f + 16.0f;
    float ninv = -1.0f / (2.0f * s * s);
    if (t < 121) { float d = (float)(t - KMEAN); w[t] = __expf(d * d * ninv); }
    __syncthreads();
    if (t == 0) {
        float sum = 0.f;
        for (int i = 0; i < 121; ++i) sum += w[i];
        float inv = 1.f / sum, run = 0.f;
        for (int i = 0; i < 121; ++i) { float wi = w[i] * inv; w[i] = wi; run += wi; P[i] = run; }
    }
    __syncthreads();
    ws[t] = (t < 121) ? w[t] : 0.f;                       // taps, 121..127 = 0
    #pragma unroll
    for (int j = 0; j < 4; ++j) {
        int o = t * 4 + j;
        ws[128 + o] = (o <= 59)  ? P[59 - o]          : 0.f;   // L
        ws[640 + o] = (o >= 452) ? (1.f - P[571 - o]) : 0.f;   // R
    }
}

// ---------------------------------------------------------------------------
// Kernel 2: FUSED blur. Block = one plane's 16-col band x all 512 rows.
// Phase 1 (hblur): thread t -> rows 2t,2t+1, cols c0..c0+15. Horizontal
//   zero-pad is SALU-only: per quad k the col index colq = c0-60+4k is
//   wave-uniform; c0%4==0 -> quads never straddle edges -> OOB quads get
//   soffset=0x7fff0000 (SRD returns 0). Replicate restored by x0*L/xN*R.
//   Output packed fp16 (rows 2t,2t+1) -> LDS[m=t][c], stride 17 dwords
//   (2-way bank alias = free).
// Phase 2 (vblur): thread = col (t&15) x 32 rows (g=t>>4). r10-proven W[36]
//   f32 register window, refilled 2 pair-dwords/chunk by ds_read_b32.
//   Vertical zero-pad via pre-zeroed LDS halo slots (m in [-32,0) u [256,304)).
//   Replicate restored by L/R corrections (same tables, vertical identity).
// ---------------------------------------------------------------------------
__global__ __launch_bounds__(256) void fused_blur(const float* __restrict__ x,
                                                  const float* __restrict__ ws,
                                                  float* __restrict__ out) {
    const int b     = blockIdx.x;            // 0..767 = 24 planes x 32 bands
    const int plane = b >> 5;
    const int c0    = (b & 31) * 16;         // band's first output col
    const int t     = threadIdx.x;           // 0..255

    // LDS tmp: ls = m + 32 (m = row pair, -32..303), stride 17 dwords
    __shared__ unsigned lds[336 * 17];
    #pragma unroll
    for (int i = t; i < 32 * 17; i += 256) lds[i] = 0u;              // m < 0
    #pragma unroll
    for (int i = t; i < 48 * 17; i += 256) lds[288 * 17 + i] = 0u;   // m >= 256

    const float* xp = x + (size_t)plane * (IMW * IMH);
    float*       op = out + (size_t)plane * (IMW * IMH);
    const i32x4 srdX = make_srd(xp, IMW * IMH * 4);   // 1 MiB plane
    const i32x4 srdO = make_srd(op, IMW * IMH * 4);
    const f32x4* __restrict__ w4 = (const f32x4*)ws;
    const float* __restrict__ Lf = ws + 128;
    const float* __restrict__ Rf = ws + 640;

    // ---------------- Phase 1: horizontal ----------------
    float res[2][16];
    #pragma unroll
    for (int rr = 0; rr < 2; ++rr) {
        const int row = 2 * t + rr;
        const int vo  = row * (IMW * 4);

        float W[20];                         // 5-quad window, cols c0-60+4c ..+19
        #pragma unroll
        for (int k = 0; k < 5; ++k) {
            int colq = c0 - 60 + 4 * k;                       // uniform (SALU)
            int soff = (colq >= 0 && colq <= IMW - 4) ? colq * 4 : 0x7fff0000;
            f32x4 q = buf_load_x4(srdX, vo, soff, 0);
            W[4*k] = q.x; W[4*k+1] = q.y; W[4*k+2] = q.z; W[4*k+3] = q.w;
        }
        float a[16];
        #pragma unroll
        for (int j = 0; j < 16; ++j) a[j] = 0.f;

        #pragma unroll
        for (int c = 0; c < 31; ++c) {       // taps 4c..4c+3 (121..123 w=0)
            f32x4 w = w4[c];                 // uniform -> s_load_dwordx4
            #pragma unroll
            for (int j = 0; j < 16; ++j)
                a[j] += w.x*W[j] + w.y*W[j+1] + w.z*W[j+2] + w.w*W[j+3];
            if (c < 30) {
                int colq = c0 - 60 + 4 * (c + 5);             // uniform
                int soff = (colq >= 0 && colq <= IMW - 4) ? colq * 4 : 0x7fff0000;
                f32x4 q = buf_load_x4(srdX, vo, soff, 0);
                #pragma unroll
                for (int d = 0; d < 16; ++d) W[d] = W[d + 4];
                W[16] = q.x; W[17] = q.y; W[18] = q.z; W[19] = q.w;
            }
        }
        // replicate-pad corrections (L/R table entries are uniform -> s_load)
        float x0 = buf_load_f32(srdX, vo, 0, 0);
        float xN = buf_load_f32(srdX, vo + (IMW - 1) * 4, 0, 0);
        #pragma unroll
        for (int j = 0; j < 16; ++j)
            res[rr][j] = a[j] + x0 * Lf[c0 + j] + xN * Rf[c0 + j];
    }
    {   // pack (row 2t, row 2t+1) per col -> LDS m = t
        unsigned* dst = &lds[(t + 32) * 17];
        #pragma unroll
        for (int j = 0; j < 16; ++j) {
            HU p; p.h = __builtin_amdgcn_cvt_pkrtz(res[0][j], res[1][j]);
            dst[j] = p.u;
        }
    }
    __syncthreads();

    // ---------------- Phase 2: vertical ----------------
    const int cc = t & 15;                   // local col
    const int g  = t >> 4;                   // row group 0..15
    const int r0 = g * 32;                   // output rows r0..r0+31
    const int M0 = (r0 - KMEAN) >> 1;        // first pair (r0-60 even)
    const int lb = (M0 + 32) * 17 + cc;      // LDS dword index base

    float W[36];                             // rows r0-60+4c4 .. +35
    #pragma unroll
    for (int d = 0; d < 18; ++d) {
        f32x2 u = h2unpk(lds[lb + d * 17]);
        W[2*d] = u.x; W[2*d+1] = u.y;
    }
    float acc[32];
    #pragma unroll
    for (int i = 0; i < 32; ++i) acc[i] = 0.f;

    #pragma unroll
    for (int c4 = 0; c4 < 30; ++c4) {
        f32x4 w = w4[c4];                    // uniform -> s_load
        #pragma unroll
        for (int i = 0; i < 32; ++i)
            acc[i] += w.x*W[i] + w.y*W[i+1] + w.z*W[i+2] + w.w*W[i+3];
        f32x2 ua = h2unpk(lds[lb + (2*c4 + 18) * 17]);
        f32x2 ub = h2unpk(lds[lb + (2*c4 + 19) * 17]);
        #pragma unroll
        for (int d = 0; d < 32; ++d) W[d] = W[d + 4];
        W[32] = ua.x; W[33] = ua.y; W[34] = ub.x; W[35] = ub.y;
    }
    {   // final chunk c4 = 30: taps 120..123 (121..123 zero)
        f32x4 w = w4[30];
        #pragma unroll
        for (int i = 0; i < 32; ++i)
            acc[i] += w.x*W[i] + w.y*W[i+1] + w.z*W[i+2] + w.w*W[i+3];
    }

    // vertical replicate corrections: row 0 = lo(m=0), row 511 = hi(m=255)
    f32x2 e0 = h2unpk(lds[(0   + 32) * 17 + cc]);
    f32x2 eN = h2unpk(lds[(255 + 32) * 17 + cc]);
    const float T0 = e0.x, TN = eN.y;
    const int col = c0 + cc;
    #pragma unroll
    for (int i = 0; i < 32; ++i) {
        float v = acc[i] + Lf[r0 + i] * T0 + Rf[r0 + i] * TN;
        buf_store_f32(v, srdO, (r0 + i) * (IMW * 4) + col * 4, 0, 0);
    }
}

// ---------------------------------------------------------------------------
extern "C" void kernel_launch(void* const* d_in, const int* in_sizes, int n_in,
                              void* d_out, int out_size, void* d_ws, size_t ws_size,
                              hipStream_t stream) {
    const float* x     = (const float*)d_in[0];
    const float* sigma = (const float*)d_in[1];
    float* out = (float*)d_out;

    float* ws_f = (float*)d_ws;   // [0,128) taps | [128,640) L | [640,1152) R

    weights_kernel<<<1, 128, 0, stream>>>(sigma, ws_f);
    fused_blur<<<NPLANES * 32, 256, 0, stream>>>(x, ws_f, out);
}

// Round 13
// 144.966 us; speedup vs baseline: 1.4829x; 1.4829x over previous
//
#include <hip/hip_runtime.h>

#define IMW 512
#define IMH 512
#define NPLANES 24
#define XSTB 1536          // padded col/row stride: 768 f16 = 1536 B
// ws byte offsets
#define WS_L   0           // L[512] fp32 (prefix corrections, quantized taps)
#define WS_R   2048        // R[512] fp32
#define WS_AT  4096        // Toeplitz At[16][160] f16 (5120 B)
#define WS_E0  9216        // x[row][0] fp32 [12288]
#define WS_EN  58368       // x[row][511] fp32 [12288]
#define WS_XF  131072      // x_f16 padded: [12288 rows][768] f16 (18.9 MB)
#define WS_TT  19005440    // tmp_t f16 col-major padded: [12288 cols][768] (18.9 MB)

typedef float    f32x4 __attribute__((ext_vector_type(4)));
typedef float    f32x2 __attribute__((ext_vector_type(2)));
typedef int      i32x4 __attribute__((ext_vector_type(4)));
typedef unsigned u32x2 __attribute__((ext_vector_type(2)));
typedef __fp16   f16x2 __attribute__((ext_vector_type(2)));
typedef __fp16   f16x8 __attribute__((ext_vector_type(8)));

__device__ f32x4 buf_load_x4(i32x4, int, int, int) __asm("llvm.amdgcn.raw.buffer.load.v4f32");
__device__ unsigned buf_load_u32(i32x4, int, int, int) __asm("llvm.amdgcn.raw.buffer.load.i32");
__device__ float buf_load_f32(i32x4, int, int, int) __asm("llvm.amdgcn.raw.buffer.load.f32");
__device__ void buf_store_f32(float, i32x4, int, int, int) __asm("llvm.amdgcn.raw.buffer.store.f32");
__device__ void buf_store_x2u(u32x2, i32x4, int, int, int) __asm("llvm.amdgcn.raw.buffer.store.v2i32");

__device__ __forceinline__ i32x4 make_srd(const void* p, int bytes) {
    union { const void* p; unsigned u[2]; } a; a.p = p;
    i32x4 r;
    r.x = (int)__builtin_amdgcn_readfirstlane((int)a.u[0]);
    r.y = (int)__builtin_amdgcn_readfirstlane((int)a.u[1]);
    r.z = bytes; r.w = 0x00020000;
    return r;
}
__device__ __forceinline__ int rfl(int v) { return __builtin_amdgcn_readfirstlane(v); }

union HU { unsigned u; f16x2 h; };
union FU { f32x4 f; f16x8 h; };

__device__ __forceinline__ unsigned pk(float a, float b) {
    HU h; h.h = __builtin_amdgcn_cvt_pkrtz(a, b); return h.u;   // lo = a
}
__device__ __forceinline__ f32x2 h2unpk(unsigned u) {
    HU a; a.u = u; f32x2 r; r.x = (float)a.h.x; r.y = (float)a.h.y; return r;
}

// ---------------------------------------------------------------------------
// Kernel 1: f16-quantized taps wq (r10-proven renormalization), prefix Pq ->
//   L[o]=Pq[59-o] (o<=59), R[o]=Sq-Pq[571-o] (o>=452)  [shared by both axes]
//   Toeplitz At[i][kap]=wq[kap-i] (0<=kap-i<=120 else 0), f16 [16][160].
// ---------------------------------------------------------------------------
__global__ __launch_bounds__(128) void weights_kernel(const float* __restrict__ sigma,
                                                      char* __restrict__ wsb) {
    __shared__ float w[121];
    __shared__ float hqf[124];
    __shared__ float Pq[121];
    int t = threadIdx.x;
    float s = sigma[0] * 8.0f + 16.0f;
    float ninv = -1.0f / (2.0f * s * s);
    if (t < 121) { float d = (float)(t - 60); w[t] = __expf(d * d * ninv); }
    __syncthreads();
    if (t == 0) {
        float sum = 0.f;
        for (int i = 0; i < 121; ++i) sum += w[i];
        float inv = 1.f / sum;
        float S2 = 0.f;
        for (int i = 0; i < 121; ++i) S2 += (float)(__fp16)(w[i] * inv);
        float i2 = 1.f / S2, run = 0.f;
        for (int i = 0; i < 121; ++i) {
            float q = (float)(__fp16)(w[i] * inv * i2);
            hqf[i] = q; run += q; Pq[i] = run;
        }
        hqf[121] = 0.f; hqf[122] = 0.f; hqf[123] = 0.f;
    }
    __syncthreads();
    float* Lp = (float*)(wsb + WS_L);
    float* Rp = (float*)(wsb + WS_R);
    float Sq = Pq[120];
    #pragma unroll
    for (int j = 0; j < 4; ++j) {
        int o = t * 4 + j;
        Lp[o] = (o <= 59)  ? Pq[59 - o]        : 0.f;
        Rp[o] = (o >= 452) ? (Sq - Pq[571 - o]) : 0.f;
    }
    __fp16* At = (__fp16*)(wsb + WS_AT);
    #pragma unroll
    for (int e = 0; e < 20; ++e) {
        int idx = t * 20 + e;
        int i = idx / 160, k = idx - i * 160, d = k - i;
        At[idx] = (__fp16)((d >= 0 && d <= 120) ? hqf[d] : 0.f);
    }
}

// ---------------------------------------------------------------------------
// Kernel 2: convert x -> padded f16 rows (zeros in halo slots [0,60) and
// [572,768)) + edge vectors E0/EN (fp32 col 0 / col 511 per row).
// Block = 2 rows; 128 thr/row: t<64 convert 8 cols, t in [64,96) zero pads.
// ---------------------------------------------------------------------------
__global__ __launch_bounds__(256) void xcvt(const float* __restrict__ x,
                                            char* __restrict__ wsb) {
    int b = blockIdx.x;                       // 0..6143
    int t = threadIdx.x;
    int row = b * 2 + (t >> 7);               // 0..12287 (= plane*512 + r)
    int tt = t & 127;
    char* xf = wsb + WS_XF + (size_t)row * XSTB;
    if (tt < 64) {
        const f32x4* xr = (const f32x4*)(x + (size_t)row * IMW);
        f32x4 qa = xr[tt * 2], qb = xr[tt * 2 + 1];
        u32x2 d0; d0.x = pk(qa.x, qa.y); d0.y = pk(qa.z, qa.w);
        u32x2 d1; d1.x = pk(qb.x, qb.y); d1.y = pk(qb.z, qb.w);
        u32x2* dst = (u32x2*)(xf + 120 + tt * 16);   // slot 60 + 8*tt
        dst[0] = d0; dst[1] = d1;
        if (tt == 0)  *(float*)(wsb + WS_E0 + (size_t)row * 4) = qa.x;
        if (tt == 63) *(float*)(wsb + WS_EN + (size_t)row * 4) = qb.w;
    } else if (tt < 96) {
        int u = tt - 64;
        #pragma unroll
        for (int e = 0; e < 2; ++e) {
            int d = u * 2 + e;                // 0..63 pad b64 units
            int byte = (d < 15) ? d * 8 : 1144 + (d - 15) * 8;
            *(unsigned long long*)(xf + byte) = 0ULL;
        }
    }
}

// ---------------------------------------------------------------------------
// Kernel 3: zero tmp_t pad slots (re-poisoned to 0xAA every launch).
// ---------------------------------------------------------------------------
__global__ __launch_bounds__(256) void fillpads(char* __restrict__ wsb) {
    int u = blockIdx.x * 256 + threadIdx.x;   // 0..786431
    int col = u >> 6, d = u & 63;
    int byte = (d < 15) ? d * 8 : 1144 + (d - 15) * 8;
    *(unsigned long long*)(wsb + WS_TT + (size_t)col * XSTB + byte) = 0ULL;
}

// ---------------------------------------------------------------------------
// Kernel 4: horizontal pass as MFMA. Wave = 16-row x 16-outcol tile.
// D[r][n] = sum_kap A[r][kap] * B[kap][n]; A = x_f16 rows (natural A-frag:
// row = lane&15, k = quad*8+j contiguous cols), B = Toeplitz At[n][kap]
// (b128 frags). 5 chunks of K=32. Zero-pad free via padded x_f16; replicate
// restored by E0*L + EN*R. D (col=lane&15, row=quad*4+reg) packs 4 rows of
// one col -> ONE b64 into col-major tmp_t (native transpose, no LDS).
// ---------------------------------------------------------------------------
__global__ __launch_bounds__(256) void hblur_mfma(char* __restrict__ wsb) {
    int b = blockIdx.x;                       // 6144 = 24 planes x 32 rt x 8 cg
    int plane = b >> 8, rem = b & 255;
    int rt = rem >> 3, cg = rem & 7;
    int w = threadIdx.x >> 6, lane = threadIdx.x & 63;
    int ct = cg * 4 + w;
    int r0 = rt * 16, c0 = ct * 16;
    int n = lane & 15, q = lane >> 4;

    const i32x4 srd = make_srd(wsb, 0x7FFFFFF0);
    const int voffA = n * XSTB + q * 16;      // row = lane&15, col chunk offset
    const int soffA = rfl(WS_XF + (plane * 512 + r0) * XSTB + c0 * 2);
    const int voffB = n * 320 + q * 16;       // At[n][kap]
    f32x4 acc; acc.x = 0.f; acc.y = 0.f; acc.z = 0.f; acc.w = 0.f;
    #pragma unroll
    for (int c = 0; c < 5; ++c) {
        FU a, bb;
        a.f  = buf_load_x4(srd, voffA, soffA + 64 * c, 0);
        bb.f = buf_load_x4(srd, voffB, WS_AT + 64 * c, 0);
        acc = __builtin_amdgcn_mfma_f32_16x16x32_f16(a.h, bb.h, acc, 0, 0, 0);
    }
    // replicate corrections: rows r0+4q+reg, col c0+n
    f32x4 e0 = buf_load_x4(srd, q * 16, rfl(WS_E0 + (plane * 512 + r0) * 4), 0);
    f32x4 eN = buf_load_x4(srd, q * 16, rfl(WS_EN + (plane * 512 + r0) * 4), 0);
    float lh = buf_load_f32(srd, n * 4, rfl(WS_L + c0 * 4), 0);
    float rh = buf_load_f32(srd, n * 4, rfl(WS_R + c0 * 4), 0);
    acc.x += e0.x * lh + eN.x * rh;
    acc.y += e0.y * lh + eN.y * rh;
    acc.z += e0.z * lh + eN.z * rh;
    acc.w += e0.w * lh + eN.w * rh;
    // pack 4 rows of col c0+n -> b64 at tmp_t[col][slot 60+r0+4q]
    u32x2 st; st.x = pk(acc.x, acc.y); st.y = pk(acc.z, acc.w);
    int soffS = rfl(WS_TT + (plane * 512 + c0) * XSTB + 120 + r0 * 2);
    buf_store_x2u(st, srd, n * XSTB + q * 8, soffS, 0);
}

// ---------------------------------------------------------------------------
// Kernel 5: vertical pass as MFMA. Wave = 16-row x 16-col tile.
// D[i][n] = sum_kap At[i][kap] * tmp[r0-60+kap][c0+n]; A = Toeplitz,
// B = tmp_t col-major (b128 = 8 consecutive rows of col c0+n). Zero-pad free
// via tmp_t pad slots; replicate restored by L[r]*tmp[0][c] + R[r]*tmp[511][c].
// D rows quad*4+reg of col c0+n -> 4 coalesced fp32 stores.
// ---------------------------------------------------------------------------
__global__ __launch_bounds__(256) void vblur_mfma(char* __restrict__ wsb,
                                                  float* __restrict__ out) {
    int b = blockIdx.x;                       // 6144 = 24 planes x 32 ct x 8 rg
    int plane = b >> 8, rem = b & 255;
    int ct = rem >> 3, rg = rem & 7;
    int w = threadIdx.x >> 6, lane = threadIdx.x & 63;
    int rt = rg * 4 + w;
    int r0 = rt * 16, c0 = ct * 16;
    int n = lane & 15, q = lane >> 4;

    const i32x4 srd = make_srd(wsb, 0x7FFFFFF0);
    const i32x4 srdO = make_srd(out, IMW * IMH * NPLANES * 4);
    const int voffA = n * 320 + q * 16;       // At[i=lane&15][kap]
    const int voffB = n * XSTB + q * 16;      // tmp_t[c0+n][slot r0 + kap]
    const int soffB = rfl(WS_TT + (plane * 512 + c0) * XSTB + r0 * 2);
    f32x4 acc; acc.x = 0.f; acc.y = 0.f; acc.z = 0.f; acc.w = 0.f;
    #pragma unroll
    for (int c = 0; c < 5; ++c) {
        FU a, bb;
        a.f  = buf_load_x4(srd, voffA, WS_AT + 64 * c, 0);
        bb.f = buf_load_x4(srd, voffB, soffB + 64 * c, 0);
        acc = __builtin_amdgcn_mfma_f32_16x16x32_f16(a.h, bb.h, acc, 0, 0, 0);
    }
    // replicate corrections
    f32x4 lv = buf_load_x4(srd, q * 16, rfl(WS_L + r0 * 4), 0);
    f32x4 rv = buf_load_x4(srd, q * 16, rfl(WS_R + r0 * 4), 0);
    int sc = rfl(WS_TT + (plane * 512 + c0) * XSTB);
    f32x2 t0 = h2unpk(buf_load_u32(srd, n * XSTB, sc + 120, 0));    // lo = row 0
    f32x2 tn = h2unpk(buf_load_u32(srd, n * XSTB, sc + 1140, 0));   // hi = row 511
    float T0 = t0.x, TN = tn.y;
    acc.x += lv.x * T0 + rv.x * TN;
    acc.y += lv.y * T0 + rv.y * TN;
    acc.z += lv.z * T0 + rv.z * TN;
    acc.w += lv.w * T0 + rv.w * TN;
    // store: rows r0+4q+j, col c0+n
    int soffO = rfl((plane * 262144 + r0 * 512 + c0) * 4);
    buf_store_f32(acc.x, srdO, n * 4 + q * 8192, soffO, 0);
    buf_store_f32(acc.y, srdO, n * 4 + q * 8192, soffO + 2048, 0);
    buf_store_f32(acc.z, srdO, n * 4 + q * 8192, soffO + 4096, 0);
    buf_store_f32(acc.w, srdO, n * 4 + q * 8192, soffO + 6144, 0);
}

// ---------------------------------------------------------------------------
extern "C" void kernel_launch(void* const* d_in, const int* in_sizes, int n_in,
                              void* d_out, int out_size, void* d_ws, size_t ws_size,
                              hipStream_t stream) {
    const float* x     = (const float*)d_in[0];
    const float* sigma = (const float*)d_in[1];
    float* out = (float*)d_out;
    char* wsb = (char*)d_ws;

    weights_kernel<<<1, 128, 0, stream>>>(sigma, wsb);
    xcvt<<<NPLANES * IMH / 2, 256, 0, stream>>>(x, wsb);
    fillpads<<<3072, 256, 0, stream>>>(wsb);
    hblur_mfma<<<NPLANES * 256, 256, 0, stream>>>(wsb);
    vblur_mfma<<<NPLANES * 256, 256, 0, stream>>>(wsb, out);
}